// Round 1
// baseline (2224.612 us; speedup 1.0000x reference)
//
#include <hip/hip_runtime.h>
#include <math.h>

#define BATCH   512
#define NSLOTS  65536
#define DIM     256

#define NGROUPS 32            // column groups over N
#define CPG     2048          // columns (slots) per group
#define TI      128           // slot tile inside a group
#define NTILES  (CPG/TI)      // 16
#define RB      32            // query rows per block
#define NROWG   (BATCH/RB)    // 16

// workspace layout (float offsets)
#define WS_QN   0
#define WS_RN   (WS_QN + BATCH*DIM)        // 131072
#define WS_WST  (WS_RN + NSLOTS)           // +65536 : per-row write-weight stats (float4/row)
#define WS_RST  (WS_WST + BATCH*4)         // per-row content softmax stats (float4/row)
#define WS_SST  (WS_RST + BATCH*4)         // per-(group,row) partial stats (float4)
// total = WS_SST + NGROUPS*BATCH*4 floats ~= 1.02 MB

// ---------------- query L2 norm ----------------
__global__ __launch_bounds__(256) void k_qnorm(const float* __restrict__ q, float* __restrict__ qn){
  int b = blockIdx.x, t = threadIdx.x;
  float v = q[b*DIM + t];
  __shared__ float red[256];
  red[t] = v*v;
  __syncthreads();
  for (int s = 128; s > 0; s >>= 1){
    if (t < s) red[t] += red[t+s];
    __syncthreads();
  }
  float n = fmaxf(sqrtf(red[0]), 1e-12f);
  qn[b*DIM + t] = v / n;
}

// ---------------- memory row inverse norms ----------------
__global__ __launch_bounds__(256) void k_rnorm(const float* __restrict__ mem, float* __restrict__ rn){
  int t = threadIdx.x;
  int lane = t & 63;
  int row = blockIdx.x*4 + (t >> 6);
  float4 v = ((const float4*)(mem + (size_t)row*DIM))[lane];
  float s = v.x*v.x + v.y*v.y + v.z*v.z + v.w*v.w;
  #pragma unroll
  for (int off = 32; off > 0; off >>= 1) s += __shfl_xor(s, off, 64);
  if (lane == 0) rn[row] = 1.0f / fmaxf(sqrtf(s), 1e-12f);
}

// ---------------- per-row write-weight stats: inv_denom, m, invZ ----------------
__global__ __launch_bounds__(256) void k_wstats(const float* __restrict__ prev, const float* __restrict__ sw,
                                                float* __restrict__ wst){
  int b = blockIdx.x, t = threadIdx.x;
  float s0 = sw[0], s1 = sw[1], s2 = sw[2];
  const float* p = prev + (size_t)b*NSLOTS;
  float lsum = 0.f, lmax = 0.f;   // sharp >= 0
  for (int i = t; i < NSLOTS; i += 256){
    float a  = (i > 0) ? p[i-1] : 0.f;
    float c  = (i < NSLOTS-1) ? p[i+1] : 0.f;
    float sh = s0*a + s1*p[i] + s2*c;
    float sharp = sh*sqrtf(sh);           // sh^1.5, sh >= 0
    lsum += sharp;
    lmax = fmaxf(lmax, sharp);
  }
  __shared__ float rs[256], rm[256];
  rs[t] = lsum; rm[t] = lmax;
  __syncthreads();
  for (int s = 128; s > 0; s >>= 1){
    if (t < s){ rs[t] += rs[t+s]; rm[t] = fmaxf(rm[t], rm[t+s]); }
    __syncthreads();
  }
  float inv_d = 1.0f / (rs[0] + 1e-8f);
  float m = rm[0] * inv_d;                // max(w_loc)
  __syncthreads();
  float lz = 0.f;
  for (int i = t; i < NSLOTS; i += 256){
    float a  = (i > 0) ? p[i-1] : 0.f;
    float c  = (i < NSLOTS-1) ? p[i+1] : 0.f;
    float sh = s0*a + s1*p[i] + s2*c;
    float sharp = sh*sqrtf(sh);
    lz += expf(sharp*inv_d - m);
  }
  rs[t] = lz;
  __syncthreads();
  for (int s = 128; s > 0; s >>= 1){
    if (t < s) rs[t] += rs[t+s];
    __syncthreads();
  }
  if (t == 0){
    float4 o; o.x = inv_d; o.y = m; o.z = 1.0f/rs[0]; o.w = 0.f;
    ((float4*)wst)[b] = o;
  }
}

// ---------------- sim pass 1: per-(group,row) online stats {max, sumexp, argmax} ----------------
__global__ __launch_bounds__(256) void k_sim1(const float* __restrict__ qn, const float* __restrict__ mem,
                                              const float* __restrict__ rn, float* __restrict__ sst){
  int rg = blockIdx.x, cg = blockIdx.y;
  int t = threadIdx.x;
  int tx = t & 31, ty = t >> 5;
  int row0 = rg * RB;
  __shared__ float qT[DIM][36];   // qT[d][r], stride 36 -> float4-aligned rows
  __shared__ float mt[TI][33];    // mem tile [i][d-chunk], stride 33 conflict-free
  __shared__ float s_rmax[RB];
  __shared__ float s_rsum[RB];
  __shared__ int   s_ridx[RB];

  for (int idx = t; idx < RB*DIM; idx += 256){
    int r = idx >> 8, d = idx & 255;
    qT[d][r] = qn[(row0 + r)*DIM + d];
  }
  if (t < RB){ s_rmax[t] = -1e30f; s_rsum[t] = 0.f; s_ridx[t] = 0; }
  __syncthreads();

  for (int tile = 0; tile < NTILES; ++tile){
    int i0 = cg*CPG + tile*TI;
    float acc[4][4];
    #pragma unroll
    for (int j=0;j<4;++j){
      #pragma unroll
      for (int k=0;k<4;++k) acc[j][k] = 0.f;
    }
    for (int dc = 0; dc < DIM; dc += 32){
      __syncthreads();
      #pragma unroll
      for (int rep = 0; rep < 16; ++rep){
        int idx = rep*256 + t;
        int i = idx >> 5, d = idx & 31;
        mt[i][d] = mem[(size_t)(i0 + i)*DIM + dc + d];
      }
      __syncthreads();
      #pragma unroll
      for (int d = 0; d < 32; ++d){
        float4 qv = *(const float4*)&qT[dc + d][4*ty];
        float m0 = mt[tx][d], m1 = mt[tx+32][d], m2 = mt[tx+64][d], m3 = mt[tx+96][d];
        acc[0][0] += qv.x*m0; acc[0][1] += qv.x*m1; acc[0][2] += qv.x*m2; acc[0][3] += qv.x*m3;
        acc[1][0] += qv.y*m0; acc[1][1] += qv.y*m1; acc[1][2] += qv.y*m2; acc[1][3] += qv.y*m3;
        acc[2][0] += qv.z*m0; acc[2][1] += qv.z*m1; acc[2][2] += qv.z*m2; acc[2][3] += qv.z*m3;
        acc[3][0] += qv.w*m0; acc[3][1] += qv.w*m1; acc[3][2] += qv.w*m2; acc[3][3] += qv.w*m3;
      }
    }
    float rnv[4];
    #pragma unroll
    for (int k=0;k<4;++k) rnv[k] = rn[i0 + tx + 32*k];
    #pragma unroll
    for (int j = 0; j < 4; ++j){
      int r = 4*ty + j;
      float v[4];
      float tmax = -1e30f; int tidx = 0x7fffffff;
      #pragma unroll
      for (int k=0;k<4;++k){
        float s = acc[j][k]*rnv[k];
        v[k] = s;
        int ii = i0 + tx + 32*k;
        if (s > tmax || (s == tmax && ii < tidx)){ tmax = s; tidx = ii; }
      }
      #pragma unroll
      for (int off = 16; off > 0; off >>= 1){
        float om = __shfl_xor(tmax, off, 64);
        int   oi = __shfl_xor(tidx, off, 64);
        if (om > tmax || (om == tmax && oi < tidx)){ tmax = om; tidx = oi; }
      }
      float ts = 0.f;
      #pragma unroll
      for (int k=0;k<4;++k) ts += expf(v[k] - tmax);
      #pragma unroll
      for (int off = 16; off > 0; off >>= 1) ts += __shfl_xor(ts, off, 64);
      if (tx == 0){
        float rmax = s_rmax[r], rsum = s_rsum[r];
        if (tmax > rmax){
          s_rsum[r] = rsum*expf(rmax - tmax) + ts;
          s_rmax[r] = tmax;
          s_ridx[r] = tidx;
        } else {
          s_rsum[r] = rsum + ts*expf(tmax - rmax);
        }
      }
    }
  }
  __syncthreads();
  if (t < RB){
    float4 o;
    o.x = s_rmax[t]; o.y = s_rsum[t]; o.z = __int_as_float(s_ridx[t]); o.w = 0.f;
    ((float4*)sst)[cg*BATCH + row0 + t] = o;
  }
}

// ---------------- combine per-group stats into per-row {gmax, 1/gsum, argmax} ----------------
__global__ __launch_bounds__(256) void k_combine(const float* __restrict__ sst, float* __restrict__ rst){
  int row = blockIdx.x*256 + threadIdx.x;
  float gmax = -1e30f; int gidx = 0;
  for (int g = 0; g < NGROUPS; ++g){
    float4 p = ((const float4*)sst)[g*BATCH + row];
    if (p.x > gmax){ gmax = p.x; gidx = __float_as_int(p.z); }
  }
  float gsum = 0.f;
  for (int g = 0; g < NGROUPS; ++g){
    float4 p = ((const float4*)sst)[g*BATCH + row];
    gsum += p.y * expf(p.x - gmax);
  }
  float4 o; o.x = gmax; o.y = 1.0f/gsum; o.z = __int_as_float(gidx); o.w = 0.f;
  ((float4*)rst)[row] = o;
}

// ---------------- sim pass 2: recompute sim, w_content, accumulate read_content ----------------
__global__ __launch_bounds__(256) void k_sim2(const float* __restrict__ qn, const float* __restrict__ mem,
                                              const float* __restrict__ rn, const float* __restrict__ rst,
                                              float* __restrict__ outc){
  int rg = blockIdx.x, cg = blockIdx.y;
  int t = threadIdx.x;
  int tx = t & 31, ty = t >> 5;
  int row0 = rg * RB;
  __shared__ float qT[DIM][36];   // 36864 B
  __shared__ float mt[TI][17];    // 8704 B  (16-wide d chunks to fit 64KB LDS)
  __shared__ float wT[TI][36];    // 18432 B ; total 64000 B

  for (int idx = t; idx < RB*DIM; idx += 256){
    int r = idx >> 8, d = idx & 255;
    qT[d][r] = qn[(row0 + r)*DIM + d];
  }
  float gmax[4], ginv[4];
  #pragma unroll
  for (int j=0;j<4;++j){
    float4 rs = ((const float4*)rst)[row0 + 4*ty + j];
    gmax[j] = rs.x; ginv[j] = rs.y;
  }
  float accout[RB];
  #pragma unroll
  for (int r=0;r<RB;++r) accout[r] = 0.f;
  __syncthreads();

  for (int tile = 0; tile < NTILES; ++tile){
    int i0 = cg*CPG + tile*TI;
    float acc[4][4];
    #pragma unroll
    for (int j=0;j<4;++j){
      #pragma unroll
      for (int k=0;k<4;++k) acc[j][k] = 0.f;
    }
    for (int dc = 0; dc < DIM; dc += 16){
      __syncthreads();
      #pragma unroll
      for (int rep = 0; rep < 8; ++rep){
        int idx = rep*256 + t;
        int i = idx >> 4, d = idx & 15;
        mt[i][d] = mem[(size_t)(i0 + i)*DIM + dc + d];
      }
      __syncthreads();
      #pragma unroll
      for (int d = 0; d < 16; ++d){
        float4 qv = *(const float4*)&qT[dc + d][4*ty];
        float m0 = mt[tx][d], m1 = mt[tx+32][d], m2 = mt[tx+64][d], m3 = mt[tx+96][d];
        acc[0][0] += qv.x*m0; acc[0][1] += qv.x*m1; acc[0][2] += qv.x*m2; acc[0][3] += qv.x*m3;
        acc[1][0] += qv.y*m0; acc[1][1] += qv.y*m1; acc[1][2] += qv.y*m2; acc[1][3] += qv.y*m3;
        acc[2][0] += qv.z*m0; acc[2][1] += qv.z*m1; acc[2][2] += qv.z*m2; acc[2][3] += qv.z*m3;
        acc[3][0] += qv.w*m0; acc[3][1] += qv.w*m1; acc[3][2] += qv.w*m2; acc[3][3] += qv.w*m3;
      }
    }
    // w phase: w = exp(sim - gmax) * (1/gsum), stored transposed wT[i][r]
    #pragma unroll
    for (int k=0;k<4;++k){
      int ii = i0 + tx + 32*k;
      float rnv = rn[ii];
      float4 w4;
      w4.x = expf(acc[0][k]*rnv - gmax[0]) * ginv[0];
      w4.y = expf(acc[1][k]*rnv - gmax[1]) * ginv[1];
      w4.z = expf(acc[2][k]*rnv - gmax[2]) * ginv[2];
      w4.w = expf(acc[3][k]*rnv - gmax[3]) * ginv[3];
      *(float4*)&wT[tx + 32*k][4*ty] = w4;
    }
    __syncthreads();
    // accumulation: thread owns output column d = t
    for (int i = 0; i < TI; ++i){
      float v = mem[(size_t)(i0 + i)*DIM + t];
      const float4* wr = (const float4*)&wT[i][0];
      #pragma unroll
      for (int r4 = 0; r4 < 8; ++r4){
        float4 w = wr[r4];
        accout[4*r4+0] += w.x*v;
        accout[4*r4+1] += w.y*v;
        accout[4*r4+2] += w.z*v;
        accout[4*r4+3] += w.w*v;
      }
    }
    __syncthreads();
  }
  #pragma unroll
  for (int r = 0; r < RB; ++r)
    atomicAdd(&outc[(row0 + r)*DIM + t], accout[r]);
}

// ---------------- read_topk = memory[argmax] (w_topk is exactly one-hot; see analysis) ----------------
__global__ __launch_bounds__(256) void k_topk(const float* __restrict__ rst, const float* __restrict__ mem,
                                              float* __restrict__ outk){
  int b = blockIdx.x, t = threadIdx.x;
  int idx = __float_as_int(((const float4*)rst)[b].z);
  outk[b*DIM + t] = mem[(size_t)idx*DIM + t];
}

// ---------------- new_mem: fused w_write recompute + erase product + W^T @ value ----------------
__global__ __launch_bounds__(256) void k_newmem(const float* __restrict__ mem, const float* __restrict__ val,
                                                const float* __restrict__ prev, const float* __restrict__ sw,
                                                const float* __restrict__ wst, float* __restrict__ outm){
  int t = threadIdx.x;
  int i0 = blockIdx.x * 32;
  int bl = t >> 5, s = t & 31;
  float s0 = sw[0], s1 = sw[1], s2 = sw[2];
  __shared__ float wtile[8][32];
  __shared__ float eprod[32];
  float acc[32];
  #pragma unroll
  for (int r=0;r<32;++r) acc[r] = 0.f;
  if (t < 32) eprod[t] = 1.0f;
  __syncthreads();
  for (int bc = 0; bc < 64; ++bc){
    int b = bc*8 + bl;
    int i = i0 + s;
    const float* p = prev + (size_t)b*NSLOTS;
    float a  = (i > 0) ? p[i-1] : 0.f;
    float c  = (i < NSLOTS-1) ? p[i+1] : 0.f;
    float sh = s0*a + s1*p[i] + s2*c;
    float sharp = sh*sqrtf(sh);
    float4 st = ((const float4*)wst)[b];
    wtile[bl][s] = expf(sharp*st.x - st.y)*st.z;
    __syncthreads();
    if (t < 32){
      float e = eprod[t];
      #pragma unroll
      for (int q=0;q<8;++q) e *= (1.0f - 0.5f*wtile[q][t]);
      eprod[t] = e;
    }
    #pragma unroll
    for (int q = 0; q < 8; ++q){
      float v = val[(size_t)(bc*8+q)*DIM + t];
      const float4* wr = (const float4*)&wtile[q][0];
      #pragma unroll
      for (int s4 = 0; s4 < 8; ++s4){
        float4 w = wr[s4];
        acc[4*s4+0] += w.x*v;
        acc[4*s4+1] += w.y*v;
        acc[4*s4+2] += w.z*v;
        acc[4*s4+3] += w.w*v;
      }
    }
    __syncthreads();
  }
  #pragma unroll
  for (int ss = 0; ss < 32; ++ss){
    outm[(size_t)(i0+ss)*DIM + t] = mem[(size_t)(i0+ss)*DIM + t]*eprod[ss] + acc[ss];
  }
}

extern "C" void kernel_launch(void* const* d_in, const int* in_sizes, int n_in,
                              void* d_out, int out_size, void* d_ws, size_t ws_size,
                              hipStream_t stream){
  const float* mem  = (const float*)d_in[0];
  const float* qry  = (const float*)d_in[1];
  const float* val  = (const float*)d_in[2];
  const float* prev = (const float*)d_in[3];
  const float* sw   = (const float*)d_in[4];
  // d_in[5] = k : unused — w_topk is analytically one-hot at argmax(sim) for any k
  float* out = (float*)d_out;
  float* ws  = (float*)d_ws;

  float* qn  = ws + WS_QN;
  float* rn  = ws + WS_RN;
  float* wst = ws + WS_WST;
  float* rst = ws + WS_RST;
  float* sst = ws + WS_SST;

  float* out_content = out;
  float* out_topk    = out + BATCH*DIM;
  float* out_newmem  = out + 2*BATCH*DIM;

  hipMemsetAsync(out_content, 0, BATCH*DIM*sizeof(float), stream);
  hipLaunchKernelGGL(k_qnorm,  dim3(BATCH),          dim3(DIM), 0, stream, qry, qn);
  hipLaunchKernelGGL(k_rnorm,  dim3(NSLOTS/4),       dim3(256), 0, stream, mem, rn);
  hipLaunchKernelGGL(k_wstats, dim3(BATCH),          dim3(256), 0, stream, prev, sw, wst);
  hipLaunchKernelGGL(k_sim1,   dim3(NROWG, NGROUPS), dim3(256), 0, stream, qn, mem, rn, sst);
  hipLaunchKernelGGL(k_combine,dim3(2),              dim3(256), 0, stream, sst, rst);
  hipLaunchKernelGGL(k_sim2,   dim3(NROWG, NGROUPS), dim3(256), 0, stream, qn, mem, rn, rst, out_content);
  hipLaunchKernelGGL(k_topk,   dim3(BATCH),          dim3(DIM), 0, stream, rst, mem, out_topk);
  hipLaunchKernelGGL(k_newmem, dim3(NSLOTS/32),      dim3(256), 0, stream, mem, val, prev, sw, wst, out_newmem);
}

// Round 2
// 1714.695 us; speedup vs baseline: 1.2974x; 1.2974x over previous
//
#include <hip/hip_runtime.h>
#include <math.h>

#define BATCH   512
#define NSLOTS  65536
#define DIM     256

#define NGROUPS 32            // column groups over N
#define CPG     2048          // columns (slots) per group
#define TI      128           // slot tile inside a group
#define NTILES  (CPG/TI)      // 16
#define RB      32            // query rows per block
#define NROWG   (BATCH/RB)    // 16

// workspace layout (float offsets)
#define WS_QN   0
#define WS_RN   (WS_QN + BATCH*DIM)        // +131072
#define WS_WST  (WS_RN + NSLOTS)           // +65536
#define WS_DEN  (WS_WST + BATCH*4)         // +2048 : per-row content softmax denominator
#define WS_SST  (WS_DEN + BATCH)           // +512  : per-(group,row) {max, idx} float2
// total = WS_SST + NGROUPS*BATCH*2 floats  ~= 928 KB

// ---------------- query L2 norm ----------------
__global__ __launch_bounds__(256) void k_qnorm(const float* __restrict__ q, float* __restrict__ qn){
  int b = blockIdx.x, t = threadIdx.x;
  float v = q[b*DIM + t];
  __shared__ float red[256];
  red[t] = v*v;
  __syncthreads();
  for (int s = 128; s > 0; s >>= 1){
    if (t < s) red[t] += red[t+s];
    __syncthreads();
  }
  float n = fmaxf(sqrtf(red[0]), 1e-12f);
  qn[b*DIM + t] = v / n;
}

// ---------------- memory row inverse norms ----------------
__global__ __launch_bounds__(256) void k_rnorm(const float* __restrict__ mem, float* __restrict__ rn){
  int t = threadIdx.x;
  int lane = t & 63;
  int row = blockIdx.x*4 + (t >> 6);
  float4 v = ((const float4*)(mem + (size_t)row*DIM))[lane];
  float s = v.x*v.x + v.y*v.y + v.z*v.z + v.w*v.w;
  #pragma unroll
  for (int off = 32; off > 0; off >>= 1) s += __shfl_xor(s, off, 64);
  if (lane == 0) rn[row] = 1.0f / fmaxf(sqrtf(s), 1e-12f);
}

// ---------------- per-row write-weight stats: inv_denom, m, invZ ----------------
__global__ __launch_bounds__(256) void k_wstats(const float* __restrict__ prev, const float* __restrict__ sw,
                                                float* __restrict__ wst){
  int b = blockIdx.x, t = threadIdx.x;
  float s0 = sw[0], s1 = sw[1], s2 = sw[2];
  const float* p = prev + (size_t)b*NSLOTS;
  float lsum = 0.f, lmax = 0.f;   // sharp >= 0
  for (int i = t; i < NSLOTS; i += 256){
    float a  = (i > 0) ? p[i-1] : 0.f;
    float c  = (i < NSLOTS-1) ? p[i+1] : 0.f;
    float sh = s0*a + s1*p[i] + s2*c;
    float sharp = sh*sqrtf(sh);           // sh^1.5, sh >= 0
    lsum += sharp;
    lmax = fmaxf(lmax, sharp);
  }
  __shared__ float rs[256], rm[256];
  rs[t] = lsum; rm[t] = lmax;
  __syncthreads();
  for (int s = 128; s > 0; s >>= 1){
    if (t < s){ rs[t] += rs[t+s]; rm[t] = fmaxf(rm[t], rm[t+s]); }
    __syncthreads();
  }
  float inv_d = 1.0f / (rs[0] + 1e-8f);
  float m = rm[0] * inv_d;                // max(w_loc)
  __syncthreads();
  float lz = 0.f;
  for (int i = t; i < NSLOTS; i += 256){
    float a  = (i > 0) ? p[i-1] : 0.f;
    float c  = (i < NSLOTS-1) ? p[i+1] : 0.f;
    float sh = s0*a + s1*p[i] + s2*c;
    float sharp = sh*sqrtf(sh);
    lz += expf(sharp*inv_d - m);
  }
  rs[t] = lz;
  __syncthreads();
  for (int s = 128; s > 0; s >>= 1){
    if (t < s) rs[t] += rs[t+s];
    __syncthreads();
  }
  if (t == 0){
    float4 o; o.x = inv_d; o.y = m; o.z = 1.0f/rs[0]; o.w = 0.f;
    ((float4*)wst)[b] = o;
  }
}

// ---------------- fused sim pass: sim GEMM + exp + unnormalized read_content + denom + argmax ----
// No max-subtraction needed: BETA_CONTENT=1 and |sim|<=1 so exp(sim) in [e^-1, e].
__global__ __launch_bounds__(256, 4) void k_simfused(
    const float* __restrict__ qn, const float* __restrict__ mem,
    const float* __restrict__ rn, float* __restrict__ outc,
    float* __restrict__ denom, float* __restrict__ sst)
{
  int rg = blockIdx.x, cg = blockIdx.y;
  int t = threadIdx.x;
  int tx = t & 31, ty = t >> 5;      // sim-phase mapping: slots tx+32k, rows 4ty+j
  int c  = t & 63, g  = t >> 6;      // acc-phase mapping: cols 4c..4c+3, rows 8g..8g+7
  int row0 = rg * RB;

  __shared__ float qc[32][36];       //  4608 B : q chunk [d][r]
  __shared__ float mt[TI][33];       // 16896 B : mem tile [slot][d]
  __shared__ float WT[TI][36];       // 18432 B : w transposed [slot][row]
  // total 39936 B -> 4 blocks/CU

  float accout[8][4];
  #pragma unroll
  for (int a = 0; a < 8; ++a)
    #pragma unroll
    for (int b = 0; b < 4; ++b) accout[a][b] = 0.f;

  float dsum[4] = {0.f, 0.f, 0.f, 0.f};
  float tmax[4] = {-1e30f, -1e30f, -1e30f, -1e30f};
  int   tidx[4] = {0, 0, 0, 0};

  for (int tile = 0; tile < NTILES; ++tile){
    int i0 = cg*CPG + tile*TI;
    float acc[4][4];
    #pragma unroll
    for (int j = 0; j < 4; ++j)
      #pragma unroll
      for (int k = 0; k < 4; ++k) acc[j][k] = 0.f;

    for (int dc = 0; dc < DIM; dc += 32){
      __syncthreads();
      // stage q chunk (transpose): thread -> row t>>3, dims 4*(t&7)..+3
      {
        int r = t >> 3, d4 = (t & 7) * 4;
        float4 q4 = *(const float4*)&qn[(size_t)(row0 + r)*DIM + dc + d4];
        qc[d4+0][r] = q4.x; qc[d4+1][r] = q4.y; qc[d4+2][r] = q4.z; qc[d4+3][r] = q4.w;
      }
      // stage mem tile: 128 slots x 32 dims
      #pragma unroll
      for (int rep = 0; rep < 4; ++rep){
        int lin = rep*1024 + t*4;
        int i = lin >> 5, d = lin & 31;
        float4 m4 = *(const float4*)&mem[(size_t)(i0 + i)*DIM + dc + d];
        mt[i][d+0] = m4.x; mt[i][d+1] = m4.y; mt[i][d+2] = m4.z; mt[i][d+3] = m4.w;
      }
      __syncthreads();
      #pragma unroll
      for (int d = 0; d < 32; ++d){
        float4 qv = *(const float4*)&qc[d][4*ty];   // broadcast (2 addrs/wave)
        float m0 = mt[tx][d], m1 = mt[tx+32][d], m2 = mt[tx+64][d], m3 = mt[tx+96][d];
        acc[0][0] += qv.x*m0; acc[0][1] += qv.x*m1; acc[0][2] += qv.x*m2; acc[0][3] += qv.x*m3;
        acc[1][0] += qv.y*m0; acc[1][1] += qv.y*m1; acc[1][2] += qv.y*m2; acc[1][3] += qv.y*m3;
        acc[2][0] += qv.z*m0; acc[2][1] += qv.z*m1; acc[2][2] += qv.z*m2; acc[2][3] += qv.z*m3;
        acc[3][0] += qv.w*m0; acc[3][1] += qv.w*m1; acc[3][2] += qv.w*m2; acc[3][3] += qv.w*m3;
      }
    }
    // w phase: finalize sim, exp, track denom partials + exact-fp32 argmax
    #pragma unroll
    for (int k = 0; k < 4; ++k){
      int ii = i0 + tx + 32*k;
      float rv = rn[ii];
      #pragma unroll
      for (int j = 0; j < 4; ++j){
        float s = acc[j][k]*rv;
        float w = __expf(s);
        WT[tx + 32*k][4*ty + j] = w;
        dsum[j] += w;
        if (s > tmax[j] || (s == tmax[j] && ii < tidx[j])){ tmax[j] = s; tidx[j] = ii; }
      }
    }
    __syncthreads();
    // acc phase: read_unnorm[r][dcols] += W^T tile @ mem tile
    // thread owns rows 8g..8g+7, cols 4c..4c+3 ; W reads are full-wave broadcasts
    for (int i = 0; i < TI; ++i){
      float4 v  = *(const float4*)&mem[(size_t)(i0 + i)*DIM + 4*c];
      float4 w0 = *(const float4*)&WT[i][8*g];
      float4 w1 = *(const float4*)&WT[i][8*g + 4];
      accout[0][0] += w0.x*v.x; accout[0][1] += w0.x*v.y; accout[0][2] += w0.x*v.z; accout[0][3] += w0.x*v.w;
      accout[1][0] += w0.y*v.x; accout[1][1] += w0.y*v.y; accout[1][2] += w0.y*v.z; accout[1][3] += w0.y*v.w;
      accout[2][0] += w0.z*v.x; accout[2][1] += w0.z*v.y; accout[2][2] += w0.z*v.z; accout[2][3] += w0.z*v.w;
      accout[3][0] += w0.w*v.x; accout[3][1] += w0.w*v.y; accout[3][2] += w0.w*v.z; accout[3][3] += w0.w*v.w;
      accout[4][0] += w1.x*v.x; accout[4][1] += w1.x*v.y; accout[4][2] += w1.x*v.z; accout[4][3] += w1.x*v.w;
      accout[5][0] += w1.y*v.x; accout[5][1] += w1.y*v.y; accout[5][2] += w1.y*v.z; accout[5][3] += w1.y*v.w;
      accout[6][0] += w1.z*v.x; accout[6][1] += w1.z*v.y; accout[6][2] += w1.z*v.z; accout[6][3] += w1.z*v.w;
      accout[7][0] += w1.w*v.x; accout[7][1] += w1.w*v.y; accout[7][2] += w1.w*v.z; accout[7][3] += w1.w*v.w;
    }
    __syncthreads();
  }

  // reductions over tx (xor masks 1..16 stay within each 32-lane half of the wave)
  #pragma unroll
  for (int j = 0; j < 4; ++j){
    float ds = dsum[j];
    #pragma unroll
    for (int off = 16; off > 0; off >>= 1) ds += __shfl_xor(ds, off, 64);
    float tm = tmax[j]; int ti_ = tidx[j];
    #pragma unroll
    for (int off = 16; off > 0; off >>= 1){
      float om = __shfl_xor(tm, off, 64);
      int   oi = __shfl_xor(ti_, off, 64);
      if (om > tm || (om == tm && oi < ti_)){ tm = om; ti_ = oi; }
    }
    if (tx == 0){
      int row = row0 + 4*ty + j;
      atomicAdd(&denom[row], ds);
      float2 o; o.x = tm; o.y = __int_as_float(ti_);
      ((float2*)sst)[cg*BATCH + row] = o;
    }
  }
  // accumulate unnormalized read_content
  #pragma unroll
  for (int rr = 0; rr < 8; ++rr){
    int row = row0 + 8*g + rr;
    #pragma unroll
    for (int cc = 0; cc < 4; ++cc)
      atomicAdd(&outc[(size_t)row*DIM + 4*c + cc], accout[rr][cc]);
  }
}

// ---------------- finish: normalize read_content + gather read_topk = memory[argmax] ----------------
__global__ __launch_bounds__(256) void k_finish(const float* __restrict__ sst, const float* __restrict__ denom,
                                                const float* __restrict__ mem,
                                                float* __restrict__ outc, float* __restrict__ outk){
  int row = blockIdx.x, t = threadIdx.x;
  __shared__ int s_idx;
  if (t < 32){
    float2 p = ((const float2*)sst)[t*BATCH + row];
    float tm = p.x; int ti_ = __float_as_int(p.y);
    #pragma unroll
    for (int off = 16; off > 0; off >>= 1){
      float om = __shfl_xor(tm, off, 64);
      int   oi = __shfl_xor(ti_, off, 64);
      if (om > tm || (om == tm && oi < ti_)){ tm = om; ti_ = oi; }
    }
    if (t == 0) s_idx = ti_;
  }
  __syncthreads();
  float inv = 1.0f / denom[row];
  outc[(size_t)row*DIM + t] *= inv;
  outk[(size_t)row*DIM + t] = mem[(size_t)s_idx*DIM + t];
}

// ---------------- new_mem: fused w_write recompute + erase product + W^T @ value ----------------
__global__ __launch_bounds__(256) void k_newmem(const float* __restrict__ mem, const float* __restrict__ val,
                                                const float* __restrict__ prev, const float* __restrict__ sw,
                                                const float* __restrict__ wst, float* __restrict__ outm){
  int t = threadIdx.x;
  int i0 = blockIdx.x * 32;
  int bl = t >> 5, s = t & 31;
  float s0 = sw[0], s1 = sw[1], s2 = sw[2];
  __shared__ float wtile[8][32];
  __shared__ float eprod[32];
  float acc[32];
  #pragma unroll
  for (int r=0;r<32;++r) acc[r] = 0.f;
  if (t < 32) eprod[t] = 1.0f;
  __syncthreads();
  for (int bc = 0; bc < 64; ++bc){
    int b = bc*8 + bl;
    int i = i0 + s;
    const float* p = prev + (size_t)b*NSLOTS;
    float a  = (i > 0) ? p[i-1] : 0.f;
    float c  = (i < NSLOTS-1) ? p[i+1] : 0.f;
    float sh = s0*a + s1*p[i] + s2*c;
    float sharp = sh*sqrtf(sh);
    float4 st = ((const float4*)wst)[b];
    wtile[bl][s] = expf(sharp*st.x - st.y)*st.z;
    __syncthreads();
    if (t < 32){
      float e = eprod[t];
      #pragma unroll
      for (int q=0;q<8;++q) e *= (1.0f - 0.5f*wtile[q][t]);
      eprod[t] = e;
    }
    #pragma unroll
    for (int q = 0; q < 8; ++q){
      float v = val[(size_t)(bc*8+q)*DIM + t];
      const float4* wr = (const float4*)&wtile[q][0];
      #pragma unroll
      for (int s4 = 0; s4 < 8; ++s4){
        float4 w = wr[s4];
        acc[4*s4+0] += w.x*v;
        acc[4*s4+1] += w.y*v;
        acc[4*s4+2] += w.z*v;
        acc[4*s4+3] += w.w*v;
      }
    }
    __syncthreads();
  }
  #pragma unroll
  for (int ss = 0; ss < 32; ++ss){
    outm[(size_t)(i0+ss)*DIM + t] = mem[(size_t)(i0+ss)*DIM + t]*eprod[ss] + acc[ss];
  }
}

extern "C" void kernel_launch(void* const* d_in, const int* in_sizes, int n_in,
                              void* d_out, int out_size, void* d_ws, size_t ws_size,
                              hipStream_t stream){
  const float* mem  = (const float*)d_in[0];
  const float* qry  = (const float*)d_in[1];
  const float* val  = (const float*)d_in[2];
  const float* prev = (const float*)d_in[3];
  const float* sw   = (const float*)d_in[4];
  // d_in[5] = k : unused — w_topk is analytically one-hot at argmax(sim) for any k
  float* out = (float*)d_out;
  float* ws  = (float*)d_ws;

  float* qn   = ws + WS_QN;
  float* rn   = ws + WS_RN;
  float* wst  = ws + WS_WST;
  float* den  = ws + WS_DEN;
  float* sst  = ws + WS_SST;

  float* out_content = out;
  float* out_topk    = out + BATCH*DIM;
  float* out_newmem  = out + 2*BATCH*DIM;

  hipMemsetAsync(out_content, 0, BATCH*DIM*sizeof(float), stream);
  hipMemsetAsync(den, 0, BATCH*sizeof(float), stream);
  hipLaunchKernelGGL(k_qnorm,   dim3(BATCH),          dim3(DIM), 0, stream, qry, qn);
  hipLaunchKernelGGL(k_rnorm,   dim3(NSLOTS/4),       dim3(256), 0, stream, mem, rn);
  hipLaunchKernelGGL(k_wstats,  dim3(BATCH),          dim3(256), 0, stream, prev, sw, wst);
  hipLaunchKernelGGL(k_simfused,dim3(NROWG, NGROUPS), dim3(256), 0, stream, qn, mem, rn, out_content, den, sst);
  hipLaunchKernelGGL(k_finish,  dim3(BATCH),          dim3(256), 0, stream, sst, den, mem, out_content, out_topk);
  hipLaunchKernelGGL(k_newmem,  dim3(NSLOTS/32),      dim3(256), 0, stream, mem, val, prev, sw, wst, out_newmem);
}

// Round 3
// 1001.207 us; speedup vs baseline: 2.2219x; 1.7126x over previous
//
#include <hip/hip_runtime.h>
#include <math.h>

#define BATCH   512
#define NSLOTS  65536
#define DIM     256

#define RB      64            // rows per block
#define NROWG   (BATCH/RB)    // 8
#define NCG     64            // column groups
#define CPG     (NSLOTS/NCG)  // 1024 slots per group
#define ST      32            // slot tile
#define NTILES  (CPG/ST)      // 32
#define DELTA   0.009f        // 2x worst-case bf16-input sim perturbation

// workspace layout (float offsets)
#define WS_QN   0
#define WS_RN   (WS_QN + BATCH*DIM)        // +131072
#define WS_WST  (WS_RN + NSLOTS)           // +65536
#define WS_DEN  (WS_WST + BATCH*4)         // +2048
#define WS_SST  (WS_DEN + BATCH)           // +512 : [512 rows][64 cg][16 lanes][2] float2 = 8 MB
// total ~9.2 MB

typedef __attribute__((ext_vector_type(8))) short bf16x8;
typedef __attribute__((ext_vector_type(4))) float f32x4;

__device__ inline unsigned short f2b(float x){   // fp32 -> bf16 RNE
  unsigned u = __float_as_uint(x);
  unsigned r = u + 0x7FFFu + ((u >> 16) & 1u);
  return (unsigned short)(r >> 16);
}
__device__ inline float b2f(unsigned short b){
  return __uint_as_float(((unsigned)b) << 16);
}
__device__ inline float fcomp(const float4& f, int e){
  return ((const float*)&f)[e];
}

// ---------------- query L2 norm ----------------
__global__ __launch_bounds__(256) void k_qnorm(const float* __restrict__ q, float* __restrict__ qn){
  int b = blockIdx.x, t = threadIdx.x;
  float v = q[b*DIM + t];
  __shared__ float red[256];
  red[t] = v*v;
  __syncthreads();
  for (int s = 128; s > 0; s >>= 1){
    if (t < s) red[t] += red[t+s];
    __syncthreads();
  }
  float n = fmaxf(sqrtf(red[0]), 1e-12f);
  qn[b*DIM + t] = v / n;
}

// ---------------- memory row inverse norms ----------------
__global__ __launch_bounds__(256) void k_rnorm(const float* __restrict__ mem, float* __restrict__ rn){
  int t = threadIdx.x;
  int lane = t & 63;
  int row = blockIdx.x*4 + (t >> 6);
  float4 v = ((const float4*)(mem + (size_t)row*DIM))[lane];
  float s = v.x*v.x + v.y*v.y + v.z*v.z + v.w*v.w;
  #pragma unroll
  for (int off = 32; off > 0; off >>= 1) s += __shfl_xor(s, off, 64);
  if (lane == 0) rn[row] = 1.0f / fmaxf(sqrtf(s), 1e-12f);
}

// ---------------- per-row write-weight stats: inv_denom, m, invZ ----------------
__global__ __launch_bounds__(256) void k_wstats(const float* __restrict__ prev, const float* __restrict__ sw,
                                                float* __restrict__ wst){
  int b = blockIdx.x, t = threadIdx.x;
  float s0 = sw[0], s1 = sw[1], s2 = sw[2];
  const float* p = prev + (size_t)b*NSLOTS;
  float lsum = 0.f, lmax = 0.f;
  for (int i = t; i < NSLOTS; i += 256){
    float a  = (i > 0) ? p[i-1] : 0.f;
    float c  = (i < NSLOTS-1) ? p[i+1] : 0.f;
    float sh = s0*a + s1*p[i] + s2*c;
    float sharp = sh*sqrtf(sh);
    lsum += sharp;
    lmax = fmaxf(lmax, sharp);
  }
  __shared__ float rs[256], rm[256];
  rs[t] = lsum; rm[t] = lmax;
  __syncthreads();
  for (int s = 128; s > 0; s >>= 1){
    if (t < s){ rs[t] += rs[t+s]; rm[t] = fmaxf(rm[t], rm[t+s]); }
    __syncthreads();
  }
  float inv_d = 1.0f / (rs[0] + 1e-8f);
  float m = rm[0] * inv_d;
  __syncthreads();
  float lz = 0.f;
  for (int i = t; i < NSLOTS; i += 256){
    float a  = (i > 0) ? p[i-1] : 0.f;
    float c  = (i < NSLOTS-1) ? p[i+1] : 0.f;
    float sh = s0*a + s1*p[i] + s2*c;
    float sharp = sh*sqrtf(sh);
    lz += expf(sharp*inv_d - m);
  }
  rs[t] = lz;
  __syncthreads();
  for (int s = 128; s > 0; s >>= 1){
    if (t < s) rs[t] += rs[t+s];
    __syncthreads();
  }
  if (t == 0){
    float4 o; o.x = inv_d; o.y = m; o.z = 1.0f/rs[0]; o.w = 0.f;
    ((float4*)wst)[b] = o;
  }
}

// ---------------- MFMA fused sim pass ----------------
// Per block: rows rg*64..+63, slots cg*1024..+1023 in 32-slot tiles.
// Phase A: S = Q @ (M*rn)^T via mfma 16x16x32 (Q A-frags in regs, Ms slot-major LDS).
// exp (no max-subtract: |sim|<=1), per-lane top-2 sim tracking, P->Plds (bf16).
// Phase B: O += P @ M via mfma (Plds + Md d-major LDS). Unnormalized; atomics to outc.
__global__ __launch_bounds__(256, 2) void k_simfused(
    const float* __restrict__ qn, const float* __restrict__ mem,
    const float* __restrict__ rn, float* __restrict__ outc,
    float* __restrict__ denom, float* __restrict__ sst)
{
  __shared__ short Ms[32*264];    // [slot][d] scaled by rn   (16896 B; stride 264: 16B-aligned, bank-safe)
  __shared__ short Md[256*40];    // [d][slot] unscaled       (20480 B)
  __shared__ short Plds[64*40];   // [row][slot] exp(sim)     (5120 B)

  int rg = blockIdx.x, cg = blockIdx.y;
  int t = threadIdx.x;
  int w = t >> 6;            // wave id: owns rows row0+16w..+15
  int lane = t & 63;
  int l = lane & 15;         // MFMA n / m index
  int q = lane >> 4;         // MFMA quad
  int row0 = rg * RB;

  // ---- Q A-frags in registers (8 k-steps over D=256) ----
  bf16x8 qa[8];
  {
    int qrow = row0 + 16*w + l;
    #pragma unroll
    for (int kk = 0; kk < 8; ++kk){
      const float4* qp = (const float4*)&qn[(size_t)qrow*DIM + 32*kk + 8*q];
      float4 a0 = qp[0], a1 = qp[1];
      bf16x8 v;
      v[0]=(short)f2b(a0.x); v[1]=(short)f2b(a0.y); v[2]=(short)f2b(a0.z); v[3]=(short)f2b(a0.w);
      v[4]=(short)f2b(a1.x); v[5]=(short)f2b(a1.y); v[6]=(short)f2b(a1.z); v[7]=(short)f2b(a1.w);
      qa[kk] = v;
    }
  }

  f32x4 accO[16];
  #pragma unroll
  for (int c = 0; c < 16; ++c) accO[c] = (f32x4){0.f,0.f,0.f,0.f};

  float dsum[4] = {0.f,0.f,0.f,0.f};
  float tv0[4] = {-1e30f,-1e30f,-1e30f,-1e30f}, tv1[4] = {-1e30f,-1e30f,-1e30f,-1e30f};
  int   ti0[4] = {0,0,0,0}, ti1[4] = {0,0,0,0};

  for (int tile = 0; tile < NTILES; ++tile){
    int i0 = cg*CPG + tile*ST;
    __syncthreads();   // previous phase B done before restaging
    // ---- stage: read 32x256 fp32 tile once; write Ms (scaled) + Md (transposed, unscaled) ----
    #pragma unroll
    for (int rep = 0; rep < 2; ++rep){
      int id = rep*256 + t;
      int s4 = id >> 6;        // slot quad 0..7
      int dg = id & 63;        // d quad 0..63
      int slot = i0 + s4*4;
      float4 f0 = *(const float4*)&mem[(size_t)(slot+0)*DIM + dg*4];
      float4 f1 = *(const float4*)&mem[(size_t)(slot+1)*DIM + dg*4];
      float4 f2 = *(const float4*)&mem[(size_t)(slot+2)*DIM + dg*4];
      float4 f3 = *(const float4*)&mem[(size_t)(slot+3)*DIM + dg*4];
      float r0 = rn[slot+0], r1 = rn[slot+1], r2 = rn[slot+2], r3 = rn[slot+3];
      short4 p;
      p.x=(short)f2b(f0.x*r0); p.y=(short)f2b(f0.y*r0); p.z=(short)f2b(f0.z*r0); p.w=(short)f2b(f0.w*r0);
      *(short4*)&Ms[(s4*4+0)*264 + dg*4] = p;
      p.x=(short)f2b(f1.x*r1); p.y=(short)f2b(f1.y*r1); p.z=(short)f2b(f1.z*r1); p.w=(short)f2b(f1.w*r1);
      *(short4*)&Ms[(s4*4+1)*264 + dg*4] = p;
      p.x=(short)f2b(f2.x*r2); p.y=(short)f2b(f2.y*r2); p.z=(short)f2b(f2.z*r2); p.w=(short)f2b(f2.w*r2);
      *(short4*)&Ms[(s4*4+2)*264 + dg*4] = p;
      p.x=(short)f2b(f3.x*r3); p.y=(short)f2b(f3.y*r3); p.z=(short)f2b(f3.z*r3); p.w=(short)f2b(f3.w*r3);
      *(short4*)&Ms[(s4*4+3)*264 + dg*4] = p;
      #pragma unroll
      for (int e = 0; e < 4; ++e){
        short4 pt;
        pt.x=(short)f2b(fcomp(f0,e)); pt.y=(short)f2b(fcomp(f1,e));
        pt.z=(short)f2b(fcomp(f2,e)); pt.w=(short)f2b(fcomp(f3,e));
        *(short4*)&Md[(dg*4+e)*40 + s4*4] = pt;
      }
    }
    __syncthreads();

    // ---- phase A: S[16 own rows][32 slots] ----
    f32x4 S0 = (f32x4){0.f,0.f,0.f,0.f}, S1 = (f32x4){0.f,0.f,0.f,0.f};
    #pragma unroll
    for (int kk = 0; kk < 8; ++kk){
      bf16x8 b0 = *(const bf16x8*)&Ms[(l     )*264 + 32*kk + 8*q];
      bf16x8 b1 = *(const bf16x8*)&Ms[(16 + l)*264 + 32*kk + 8*q];
      S0 = __builtin_amdgcn_mfma_f32_16x16x32_bf16(qa[kk], b0, S0, 0, 0, 0);
      S1 = __builtin_amdgcn_mfma_f32_16x16x32_bf16(qa[kk], b1, S1, 0, 0, 0);
    }
    // ---- exp + top2 + P write (wave-private Plds rows) ----
    #pragma unroll
    for (int c = 0; c < 2; ++c){
      int slot = i0 + 16*c + l;
      #pragma unroll
      for (int reg = 0; reg < 4; ++reg){
        float v = (c == 0) ? S0[reg] : S1[reg];
        bool g0 = v > tv0[reg];
        bool g1 = v > tv1[reg];
        float ov0 = tv0[reg]; int oi0 = ti0[reg];
        tv1[reg] = g0 ? ov0 : (g1 ? v : tv1[reg]);
        ti1[reg] = g0 ? oi0 : (g1 ? slot : ti1[reg]);
        tv0[reg] = g0 ? v : tv0[reg];
        ti0[reg] = g0 ? slot : ti0[reg];
        unsigned short wb = f2b(__expf(v));
        dsum[reg] += b2f(wb);   // denom from the rounded weight (consistent with numerator)
        Plds[(16*w + 4*q + reg)*40 + 16*c + l] = (short)wb;
      }
    }
    __syncthreads();   // conservative: order P writes before reads

    // ---- phase B: O[16 own rows][256 d] += P @ Mtile ----
    bf16x8 pa = *(const bf16x8*)&Plds[(16*w + l)*40 + 8*q];
    #pragma unroll
    for (int ct = 0; ct < 16; ++ct){
      bf16x8 b = *(const bf16x8*)&Md[(16*ct + l)*40 + 8*q];
      accO[ct] = __builtin_amdgcn_mfma_f32_16x16x32_bf16(pa, b, accO[ct], 0, 0, 0);
    }
  }

  // ---- epilogue ----
  #pragma unroll
  for (int reg = 0; reg < 4; ++reg){
    float s = dsum[reg];
    s += __shfl_xor(s, 1, 64); s += __shfl_xor(s, 2, 64);
    s += __shfl_xor(s, 4, 64); s += __shfl_xor(s, 8, 64);
    if (l == 0) atomicAdd(&denom[row0 + 16*w + 4*q + reg], s);
  }
  #pragma unroll
  for (int reg = 0; reg < 4; ++reg){
    int row = row0 + 16*w + 4*q + reg;
    size_t base = (((size_t)row*NCG + cg)*16 + l)*2;
    float2* S2 = (float2*)sst;
    S2[base + 0] = make_float2(tv0[reg], __int_as_float(ti0[reg]));
    S2[base + 1] = make_float2(tv1[reg], __int_as_float(ti1[reg]));
  }
  #pragma unroll
  for (int ct = 0; ct < 16; ++ct){
    #pragma unroll
    for (int reg = 0; reg < 4; ++reg){
      int row = row0 + 16*w + 4*q + reg;
      atomicAdd(&outc[(size_t)row*DIM + 16*ct + l], accO[ct][reg]);
    }
  }
}

// ---------------- finish: exact-fp32 argmax recheck + normalize + topk gather ----------------
__global__ __launch_bounds__(256) void k_finish(const float* __restrict__ sst, const float* __restrict__ denom,
                                                const float* __restrict__ qn, const float* __restrict__ rn,
                                                const float* __restrict__ mem,
                                                float* __restrict__ outc, float* __restrict__ outk){
  int row = blockIdx.x, t = threadIdx.x;
  __shared__ float red[256];
  __shared__ int cnt;
  __shared__ int cidx[128];
  __shared__ float csim[128];
  __shared__ int bestIdx;
  const float2* S = (const float2*)sst + (size_t)row*NCG*16*2;
  float2 e[8];
  float lmax = -1e30f;
  #pragma unroll
  for (int k = 0; k < 8; ++k){ e[k] = S[t*8 + k]; lmax = fmaxf(lmax, e[k].x); }
  red[t] = lmax;
  __syncthreads();
  for (int s = 128; s > 0; s >>= 1){
    if (t < s) red[t] = fmaxf(red[t], red[t+s]);
    __syncthreads();
  }
  float M = red[0];
  if (t == 0) cnt = 0;
  __syncthreads();
  #pragma unroll
  for (int k = 0; k < 8; ++k){
    if (e[k].x >= M - DELTA){
      int p = atomicAdd(&cnt, 1);
      if (p < 128) cidx[p] = __float_as_int(e[k].y);
    }
  }
  __syncthreads();
  int n = min(cnt, 128);
  int wv = t >> 6, ln = t & 63;
  for (int ci = wv; ci < n; ci += 4){
    int slot = cidx[ci];
    float4 a = ((const float4*)&qn[(size_t)row*DIM])[ln];
    float4 b = ((const float4*)&mem[(size_t)slot*DIM])[ln];
    float s = a.x*b.x + a.y*b.y + a.z*b.z + a.w*b.w;
    #pragma unroll
    for (int off = 32; off > 0; off >>= 1) s += __shfl_xor(s, off, 64);
    if (ln == 0) csim[ci] = s * rn[slot];
  }
  __syncthreads();
  if (t == 0){
    float bv = -1e30f; int bi = 0x7fffffff;
    for (int i = 0; i < n; ++i){
      float v = csim[i]; int id = cidx[i];
      if (v > bv || (v == bv && id < bi)){ bv = v; bi = id; }
    }
    bestIdx = bi;
  }
  __syncthreads();
  float inv = 1.0f / denom[row];
  outc[(size_t)row*DIM + t] *= inv;
  outk[(size_t)row*DIM + t] = mem[(size_t)bestIdx*DIM + t];
}

// ---------------- new_mem: fused w_write recompute + erase product + W^T @ value ----------------
__global__ __launch_bounds__(256) void k_newmem(const float* __restrict__ mem, const float* __restrict__ val,
                                                const float* __restrict__ prev, const float* __restrict__ sw,
                                                const float* __restrict__ wst, float* __restrict__ outm){
  int t = threadIdx.x;
  int i0 = blockIdx.x * 32;
  int bl = t >> 5, s = t & 31;
  float s0 = sw[0], s1 = sw[1], s2 = sw[2];
  __shared__ float wtile[8][32];
  __shared__ float eprod[32];
  float acc[32];
  #pragma unroll
  for (int r=0;r<32;++r) acc[r] = 0.f;
  if (t < 32) eprod[t] = 1.0f;
  __syncthreads();
  for (int bc = 0; bc < 64; ++bc){
    int b = bc*8 + bl;
    int i = i0 + s;
    const float* p = prev + (size_t)b*NSLOTS;
    float a  = (i > 0) ? p[i-1] : 0.f;
    float c  = (i < NSLOTS-1) ? p[i+1] : 0.f;
    float sh = s0*a + s1*p[i] + s2*c;
    float sharp = sh*sqrtf(sh);
    float4 st = ((const float4*)wst)[b];
    wtile[bl][s] = expf(sharp*st.x - st.y)*st.z;
    __syncthreads();
    if (t < 32){
      float e = eprod[t];
      #pragma unroll
      for (int qq=0;qq<8;++qq) e *= (1.0f - 0.5f*wtile[qq][t]);
      eprod[t] = e;
    }
    #pragma unroll
    for (int qq = 0; qq < 8; ++qq){
      float v = val[(size_t)(bc*8+qq)*DIM + t];
      const float4* wr = (const float4*)&wtile[qq][0];
      #pragma unroll
      for (int s4 = 0; s4 < 8; ++s4){
        float4 wv = wr[s4];
        acc[4*s4+0] += wv.x*v;
        acc[4*s4+1] += wv.y*v;
        acc[4*s4+2] += wv.z*v;
        acc[4*s4+3] += wv.w*v;
      }
    }
    __syncthreads();
  }
  #pragma unroll
  for (int ss = 0; ss < 32; ++ss){
    outm[(size_t)(i0+ss)*DIM + t] = mem[(size_t)(i0+ss)*DIM + t]*eprod[ss] + acc[ss];
  }
}

extern "C" void kernel_launch(void* const* d_in, const int* in_sizes, int n_in,
                              void* d_out, int out_size, void* d_ws, size_t ws_size,
                              hipStream_t stream){
  const float* mem  = (const float*)d_in[0];
  const float* qry  = (const float*)d_in[1];
  const float* val  = (const float*)d_in[2];
  const float* prev = (const float*)d_in[3];
  const float* sw   = (const float*)d_in[4];
  // d_in[5] = k : unused — w_topk is analytically one-hot at argmax(sim) for any k
  float* out = (float*)d_out;
  float* ws  = (float*)d_ws;

  float* qn   = ws + WS_QN;
  float* rn   = ws + WS_RN;
  float* wst  = ws + WS_WST;
  float* den  = ws + WS_DEN;
  float* sst  = ws + WS_SST;

  float* out_content = out;
  float* out_topk    = out + BATCH*DIM;
  float* out_newmem  = out + 2*BATCH*DIM;

  hipMemsetAsync(out_content, 0, BATCH*DIM*sizeof(float), stream);
  hipMemsetAsync(den, 0, BATCH*sizeof(float), stream);
  hipLaunchKernelGGL(k_qnorm,   dim3(BATCH),       dim3(DIM), 0, stream, qry, qn);
  hipLaunchKernelGGL(k_rnorm,   dim3(NSLOTS/4),    dim3(256), 0, stream, mem, rn);
  hipLaunchKernelGGL(k_wstats,  dim3(BATCH),       dim3(256), 0, stream, prev, sw, wst);
  hipLaunchKernelGGL(k_simfused,dim3(NROWG, NCG),  dim3(256), 0, stream, qn, mem, rn, out_content, den, sst);
  hipLaunchKernelGGL(k_finish,  dim3(BATCH),       dim3(256), 0, stream, sst, den, qn, rn, mem, out_content, out_topk);
  hipLaunchKernelGGL(k_newmem,  dim3(NSLOTS/32),   dim3(256), 0, stream, mem, val, prev, sw, wst, out_newmem);
}

// Round 4
// 670.781 us; speedup vs baseline: 3.3164x; 1.4926x over previous
//
#include <hip/hip_runtime.h>
#include <math.h>

#define BATCH   512
#define NSLOTS  65536
#define DIM     256

#define RB      64            // rows per block (simfused)
#define NROWG   (BATCH/RB)    // 8
#define NCG     64            // column groups (simfused)
#define CPG     (NSLOTS/NCG)  // 1024 slots per group
#define ST      32            // slot tile
#define NTILES  (CPG/ST)      // 32
#define DELTA   0.009f        // 2x worst-case bf16-input sim perturbation

// workspace layout (float offsets)
#define WS_QN   0
#define WS_RN   (WS_QN + BATCH*DIM)            // +131072
#define WS_WST  (WS_RN + NSLOTS)               // +65536
#define WS_DEN  (WS_WST + BATCH*4)             // +2048
#define WS_SST  (WS_DEN + BATCH)               // +512 : [512][64 cg][16 lanes][2] float2 = 8 MB
#define WS_VT   (WS_SST + BATCH*NCG*16*4)      // +2097152 : value^T bf16 [256 d][512 b] = 256 KB
// total ~9.4 MB

typedef __attribute__((ext_vector_type(8))) short bf16x8;
typedef __attribute__((ext_vector_type(4))) float f32x4;

__device__ inline unsigned short f2b(float x){   // fp32 -> bf16 RNE
  unsigned u = __float_as_uint(x);
  unsigned r = u + 0x7FFFu + ((u >> 16) & 1u);
  return (unsigned short)(r >> 16);
}
__device__ inline float b2f(unsigned short b){
  return __uint_as_float(((unsigned)b) << 16);
}
__device__ inline float fcomp(const float4& f, int e){
  return ((const float*)&f)[e];
}

// ---------------- query L2 norm ----------------
__global__ __launch_bounds__(256) void k_qnorm(const float* __restrict__ q, float* __restrict__ qn){
  int b = blockIdx.x, t = threadIdx.x;
  float v = q[b*DIM + t];
  __shared__ float red[256];
  red[t] = v*v;
  __syncthreads();
  for (int s = 128; s > 0; s >>= 1){
    if (t < s) red[t] += red[t+s];
    __syncthreads();
  }
  float n = fmaxf(sqrtf(red[0]), 1e-12f);
  qn[b*DIM + t] = v / n;
}

// ---------------- memory row inverse norms ----------------
__global__ __launch_bounds__(256) void k_rnorm(const float* __restrict__ mem, float* __restrict__ rn){
  int t = threadIdx.x;
  int lane = t & 63;
  int row = blockIdx.x*4 + (t >> 6);
  float4 v = ((const float4*)(mem + (size_t)row*DIM))[lane];
  float s = v.x*v.x + v.y*v.y + v.z*v.z + v.w*v.w;
  #pragma unroll
  for (int off = 32; off > 0; off >>= 1) s += __shfl_xor(s, off, 64);
  if (lane == 0) rn[row] = 1.0f / fmaxf(sqrtf(s), 1e-12f);
}

// ---------------- value^T bf16 prep: VT[d][b] = bf16(value[b][d]) ----------------
__global__ __launch_bounds__(256) void k_prep(const float* __restrict__ val, unsigned short* __restrict__ VT){
  __shared__ __align__(16) unsigned short tile[64][68];
  int bb = (blockIdx.x >> 2)*64, dd = (blockIdx.x & 3)*64;
  int t = threadIdx.x;
  int w = t >> 6, ln = t & 63;
  #pragma unroll
  for (int k = 0; k < 4; ++k){
    int bl = w*16 + k*4 + (ln >> 4);
    int doff = (ln & 15)*4;
    float4 f = *(const float4*)&val[(size_t)(bb + bl)*DIM + dd + doff];
    tile[doff+0][bl] = f2b(f.x);
    tile[doff+1][bl] = f2b(f.y);
    tile[doff+2][bl] = f2b(f.z);
    tile[doff+3][bl] = f2b(f.w);
  }
  __syncthreads();
  #pragma unroll
  for (int k = 0; k < 4; ++k){
    int dl = w*16 + k*4 + (ln >> 4);
    int boff = (ln & 15)*4;
    *(short4*)&VT[(size_t)(dd + dl)*BATCH + bb + boff] = *(const short4*)&tile[dl][boff];
  }
}

// ---------------- per-row write-weight stats: {inv_denom, invZ} ----------------
// No max-subtraction: w_loc = sharp*inv_d in [0,1] => exp(w_loc) in [1,e].
__global__ __launch_bounds__(256) void k_wstats(const float* __restrict__ prev, const float* __restrict__ sw,
                                                float* __restrict__ wst){
  int b = blockIdx.x, t = threadIdx.x;
  float s0 = sw[0], s1 = sw[1], s2 = sw[2];
  const float* p = prev + (size_t)b*NSLOTS;
  const float4* p4 = (const float4*)p;
  __shared__ float rs[256];
  float lsum = 0.f;
  for (int i4 = t; i4 < NSLOTS/4; i4 += 256){
    float4 f = p4[i4];
    float lft = (i4 > 0) ? p[4*i4 - 1] : 0.f;
    float rgt = (i4 < NSLOTS/4 - 1) ? p[4*i4 + 4] : 0.f;
    float sh0 = s0*lft + s1*f.x + s2*f.y;
    float sh1 = s0*f.x + s1*f.y + s2*f.z;
    float sh2 = s0*f.y + s1*f.z + s2*f.w;
    float sh3 = s0*f.z + s1*f.w + s2*rgt;
    lsum += sh0*sqrtf(sh0) + sh1*sqrtf(sh1) + sh2*sqrtf(sh2) + sh3*sqrtf(sh3);
  }
  rs[t] = lsum;
  __syncthreads();
  for (int s = 128; s > 0; s >>= 1){
    if (t < s) rs[t] += rs[t+s];
    __syncthreads();
  }
  float inv_d = 1.0f / (rs[0] + 1e-8f);
  __syncthreads();
  float lz = 0.f;
  for (int i4 = t; i4 < NSLOTS/4; i4 += 256){
    float4 f = p4[i4];
    float lft = (i4 > 0) ? p[4*i4 - 1] : 0.f;
    float rgt = (i4 < NSLOTS/4 - 1) ? p[4*i4 + 4] : 0.f;
    float sh0 = s0*lft + s1*f.x + s2*f.y;
    float sh1 = s0*f.x + s1*f.y + s2*f.z;
    float sh2 = s0*f.y + s1*f.z + s2*f.w;
    float sh3 = s0*f.z + s1*f.w + s2*rgt;
    lz += __expf(sh0*sqrtf(sh0)*inv_d) + __expf(sh1*sqrtf(sh1)*inv_d)
        + __expf(sh2*sqrtf(sh2)*inv_d) + __expf(sh3*sqrtf(sh3)*inv_d);
  }
  rs[t] = lz;
  __syncthreads();
  for (int s = 128; s > 0; s >>= 1){
    if (t < s) rs[t] += rs[t+s];
    __syncthreads();
  }
  if (t == 0){
    float4 o; o.x = inv_d; o.y = 1.0f/rs[0]; o.z = 0.f; o.w = 0.f;
    ((float4*)wst)[b] = o;
  }
}

// ---------------- MFMA fused sim pass (unchanged from round 3) ----------------
__global__ __launch_bounds__(256, 2) void k_simfused(
    const float* __restrict__ qn, const float* __restrict__ mem,
    const float* __restrict__ rn, float* __restrict__ outc,
    float* __restrict__ denom, float* __restrict__ sst)
{
  __shared__ short Ms[32*264];
  __shared__ short Md[256*40];
  __shared__ short Plds[64*40];

  int rg = blockIdx.x, cg = blockIdx.y;
  int t = threadIdx.x;
  int w = t >> 6;
  int lane = t & 63;
  int l = lane & 15;
  int q = lane >> 4;
  int row0 = rg * RB;

  bf16x8 qa[8];
  {
    int qrow = row0 + 16*w + l;
    #pragma unroll
    for (int kk = 0; kk < 8; ++kk){
      const float4* qp = (const float4*)&qn[(size_t)qrow*DIM + 32*kk + 8*q];
      float4 a0 = qp[0], a1 = qp[1];
      bf16x8 v;
      v[0]=(short)f2b(a0.x); v[1]=(short)f2b(a0.y); v[2]=(short)f2b(a0.z); v[3]=(short)f2b(a0.w);
      v[4]=(short)f2b(a1.x); v[5]=(short)f2b(a1.y); v[6]=(short)f2b(a1.z); v[7]=(short)f2b(a1.w);
      qa[kk] = v;
    }
  }

  f32x4 accO[16];
  #pragma unroll
  for (int c = 0; c < 16; ++c) accO[c] = (f32x4){0.f,0.f,0.f,0.f};

  float dsum[4] = {0.f,0.f,0.f,0.f};
  float tv0[4] = {-1e30f,-1e30f,-1e30f,-1e30f}, tv1[4] = {-1e30f,-1e30f,-1e30f,-1e30f};
  int   ti0[4] = {0,0,0,0}, ti1[4] = {0,0,0,0};

  for (int tile = 0; tile < NTILES; ++tile){
    int i0 = cg*CPG + tile*ST;
    __syncthreads();
    #pragma unroll
    for (int rep = 0; rep < 2; ++rep){
      int id = rep*256 + t;
      int s4 = id >> 6;
      int dg = id & 63;
      int slot = i0 + s4*4;
      float4 f0 = *(const float4*)&mem[(size_t)(slot+0)*DIM + dg*4];
      float4 f1 = *(const float4*)&mem[(size_t)(slot+1)*DIM + dg*4];
      float4 f2 = *(const float4*)&mem[(size_t)(slot+2)*DIM + dg*4];
      float4 f3 = *(const float4*)&mem[(size_t)(slot+3)*DIM + dg*4];
      float r0 = rn[slot+0], r1 = rn[slot+1], r2 = rn[slot+2], r3 = rn[slot+3];
      short4 p;
      p.x=(short)f2b(f0.x*r0); p.y=(short)f2b(f0.y*r0); p.z=(short)f2b(f0.z*r0); p.w=(short)f2b(f0.w*r0);
      *(short4*)&Ms[(s4*4+0)*264 + dg*4] = p;
      p.x=(short)f2b(f1.x*r1); p.y=(short)f2b(f1.y*r1); p.z=(short)f2b(f1.z*r1); p.w=(short)f2b(f1.w*r1);
      *(short4*)&Ms[(s4*4+1)*264 + dg*4] = p;
      p.x=(short)f2b(f2.x*r2); p.y=(short)f2b(f2.y*r2); p.z=(short)f2b(f2.z*r2); p.w=(short)f2b(f2.w*r2);
      *(short4*)&Ms[(s4*4+2)*264 + dg*4] = p;
      p.x=(short)f2b(f3.x*r3); p.y=(short)f2b(f3.y*r3); p.z=(short)f2b(f3.z*r3); p.w=(short)f2b(f3.w*r3);
      *(short4*)&Ms[(s4*4+3)*264 + dg*4] = p;
      #pragma unroll
      for (int e = 0; e < 4; ++e){
        short4 pt;
        pt.x=(short)f2b(fcomp(f0,e)); pt.y=(short)f2b(fcomp(f1,e));
        pt.z=(short)f2b(fcomp(f2,e)); pt.w=(short)f2b(fcomp(f3,e));
        *(short4*)&Md[(dg*4+e)*40 + s4*4] = pt;
      }
    }
    __syncthreads();

    f32x4 S0 = (f32x4){0.f,0.f,0.f,0.f}, S1 = (f32x4){0.f,0.f,0.f,0.f};
    #pragma unroll
    for (int kk = 0; kk < 8; ++kk){
      bf16x8 b0 = *(const bf16x8*)&Ms[(l     )*264 + 32*kk + 8*q];
      bf16x8 b1 = *(const bf16x8*)&Ms[(16 + l)*264 + 32*kk + 8*q];
      S0 = __builtin_amdgcn_mfma_f32_16x16x32_bf16(qa[kk], b0, S0, 0, 0, 0);
      S1 = __builtin_amdgcn_mfma_f32_16x16x32_bf16(qa[kk], b1, S1, 0, 0, 0);
    }
    #pragma unroll
    for (int c = 0; c < 2; ++c){
      int slot = i0 + 16*c + l;
      #pragma unroll
      for (int reg = 0; reg < 4; ++reg){
        float v = (c == 0) ? S0[reg] : S1[reg];
        bool g0 = v > tv0[reg];
        bool g1 = v > tv1[reg];
        float ov0 = tv0[reg]; int oi0 = ti0[reg];
        tv1[reg] = g0 ? ov0 : (g1 ? v : tv1[reg]);
        ti1[reg] = g0 ? oi0 : (g1 ? slot : ti1[reg]);
        tv0[reg] = g0 ? v : tv0[reg];
        ti0[reg] = g0 ? slot : ti0[reg];
        unsigned short wb = f2b(__expf(v));
        dsum[reg] += b2f(wb);
        Plds[(16*w + 4*q + reg)*40 + 16*c + l] = (short)wb;
      }
    }
    __syncthreads();

    bf16x8 pa = *(const bf16x8*)&Plds[(16*w + l)*40 + 8*q];
    #pragma unroll
    for (int ct = 0; ct < 16; ++ct){
      bf16x8 b = *(const bf16x8*)&Md[(16*ct + l)*40 + 8*q];
      accO[ct] = __builtin_amdgcn_mfma_f32_16x16x32_bf16(pa, b, accO[ct], 0, 0, 0);
    }
  }

  #pragma unroll
  for (int reg = 0; reg < 4; ++reg){
    float s = dsum[reg];
    s += __shfl_xor(s, 1, 64); s += __shfl_xor(s, 2, 64);
    s += __shfl_xor(s, 4, 64); s += __shfl_xor(s, 8, 64);
    if (l == 0) atomicAdd(&denom[row0 + 16*w + 4*q + reg], s);
  }
  #pragma unroll
  for (int reg = 0; reg < 4; ++reg){
    int row = row0 + 16*w + 4*q + reg;
    size_t base = (((size_t)row*NCG + cg)*16 + l)*2;
    float2* S2 = (float2*)sst;
    S2[base + 0] = make_float2(tv0[reg], __int_as_float(ti0[reg]));
    S2[base + 1] = make_float2(tv1[reg], __int_as_float(ti1[reg]));
  }
  #pragma unroll
  for (int ct = 0; ct < 16; ++ct){
    #pragma unroll
    for (int reg = 0; reg < 4; ++reg){
      int row = row0 + 16*w + 4*q + reg;
      atomicAdd(&outc[(size_t)row*DIM + 16*ct + l], accO[ct][reg]);
    }
  }
}

// ---------------- finish: exact-fp32 argmax recheck + normalize + topk gather ----------------
__global__ __launch_bounds__(256) void k_finish(const float* __restrict__ sst, const float* __restrict__ denom,
                                                const float* __restrict__ qn, const float* __restrict__ rn,
                                                const float* __restrict__ mem,
                                                float* __restrict__ outc, float* __restrict__ outk){
  int row = blockIdx.x, t = threadIdx.x;
  __shared__ float red[256];
  __shared__ int cnt;
  __shared__ int cidx[128];
  __shared__ float csim[128];
  __shared__ int bestIdx;
  const float2* S = (const float2*)sst + (size_t)row*NCG*16*2;
  float2 e[8];
  float lmax = -1e30f;
  #pragma unroll
  for (int k = 0; k < 8; ++k){ e[k] = S[t*8 + k]; lmax = fmaxf(lmax, e[k].x); }
  red[t] = lmax;
  __syncthreads();
  for (int s = 128; s > 0; s >>= 1){
    if (t < s) red[t] = fmaxf(red[t], red[t+s]);
    __syncthreads();
  }
  float M = red[0];
  if (t == 0) cnt = 0;
  __syncthreads();
  #pragma unroll
  for (int k = 0; k < 8; ++k){
    if (e[k].x >= M - DELTA){
      int p = atomicAdd(&cnt, 1);
      if (p < 128) cidx[p] = __float_as_int(e[k].y);
    }
  }
  __syncthreads();
  int n = min(cnt, 128);
  int wv = t >> 6, ln = t & 63;
  for (int ci = wv; ci < n; ci += 4){
    int slot = cidx[ci];
    float4 a = ((const float4*)&qn[(size_t)row*DIM])[ln];
    float4 b = ((const float4*)&mem[(size_t)slot*DIM])[ln];
    float s = a.x*b.x + a.y*b.y + a.z*b.z + a.w*b.w;
    #pragma unroll
    for (int off = 32; off > 0; off >>= 1) s += __shfl_xor(s, off, 64);
    if (ln == 0) csim[ci] = s * rn[slot];
  }
  __syncthreads();
  if (t == 0){
    float bv = -1e30f; int bi = 0x7fffffff;
    for (int i = 0; i < n; ++i){
      float v = csim[i]; int id = cidx[i];
      if (v > bv || (v == bv && id < bi)){ bv = v; bi = id; }
    }
    bestIdx = bi;
  }
  __syncthreads();
  float inv = 1.0f / denom[row];
  outc[(size_t)row*DIM + t] *= inv;
  outk[(size_t)row*DIM + t] = mem[(size_t)bestIdx*DIM + t];
}

// ---------------- new_mem via MFMA: out = mem*erase + W^T @ value ----------------
// Block: 64 slots x 256 d. K-loop: 16 chunks of 32 batches. W chunk recomputed
// from prev (fp32 for erase product, bf16 -> LDS A operand). B frags loaded
// straight from pre-transposed VT (bf16, L2-resident).
__global__ __launch_bounds__(256) void k_newmem(const float* __restrict__ mem,
                                                const unsigned short* __restrict__ VT,
                                                const float* __restrict__ prev, const float* __restrict__ sw,
                                                const float* __restrict__ wst, float* __restrict__ outm){
  __shared__ __align__(16) short WA[64*40];   // [slot][b-local] bf16 A chunk (5120 B)
  __shared__ float ep[4][64];
  __shared__ float eprodS[64];

  int t = threadIdx.x;
  int i0 = blockIdx.x * 64;
  int sl = t & 63;          // slot-local (w-compute mapping)
  int bg = t >> 6;          // batch sub-group == wave id
  int i  = i0 + sl;
  int w = t >> 6;
  int lane = t & 63;
  int l = lane & 15, q = lane >> 4;
  float s0 = sw[0], s1 = sw[1], s2 = sw[2];

  f32x4 accO[16];
  #pragma unroll
  for (int c = 0; c < 16; ++c) accO[c] = (f32x4){0.f,0.f,0.f,0.f};
  float epl = 1.0f;

  for (int c = 0; c < 16; ++c){
    __syncthreads();                       // WA consumed by previous iteration
    bf16x8 wv;
    #pragma unroll
    for (int j = 0; j < 8; ++j){
      int b = c*32 + bg*8 + j;             // wave-uniform
      const float* p = prev + (size_t)b*NSLOTS;
      float a  = (i > 0) ? p[i-1] : 0.f;
      float ce = p[i];
      float d  = (i < NSLOTS-1) ? p[i+1] : 0.f;
      float sh = s0*a + s1*ce + s2*d;
      float sharp = sh*sqrtf(sh);
      float4 st = ((const float4*)wst)[b]; // wave-uniform -> s_load
      float wf = __expf(sharp*st.x)*st.y;
      epl *= (1.0f - 0.5f*wf);
      wv[j] = (short)f2b(wf);
    }
    *(bf16x8*)&WA[sl*40 + bg*8] = wv;
    __syncthreads();
    bf16x8 af = *(const bf16x8*)&WA[(16*w + l)*40 + 8*q];
    #pragma unroll
    for (int ct = 0; ct < 16; ++ct){
      bf16x8 bfg = *(const bf16x8*)&VT[(size_t)(16*ct + l)*BATCH + c*32 + 8*q];
      accO[ct] = __builtin_amdgcn_mfma_f32_16x16x32_bf16(af, bfg, accO[ct], 0, 0, 0);
    }
  }
  ep[bg][sl] = epl;
  __syncthreads();
  if (t < 64) eprodS[t] = ep[0][t]*ep[1][t]*ep[2][t]*ep[3][t];
  __syncthreads();

  #pragma unroll
  for (int reg = 0; reg < 4; ++reg){
    int slot = i0 + 16*w + 4*q + reg;
    float e = eprodS[16*w + 4*q + reg];
    #pragma unroll
    for (int ct = 0; ct < 16; ++ct){
      int d = 16*ct + l;
      outm[(size_t)slot*DIM + d] = mem[(size_t)slot*DIM + d]*e + accO[ct][reg];
    }
  }
}

extern "C" void kernel_launch(void* const* d_in, const int* in_sizes, int n_in,
                              void* d_out, int out_size, void* d_ws, size_t ws_size,
                              hipStream_t stream){
  const float* mem  = (const float*)d_in[0];
  const float* qry  = (const float*)d_in[1];
  const float* val  = (const float*)d_in[2];
  const float* prev = (const float*)d_in[3];
  const float* sw   = (const float*)d_in[4];
  // d_in[5] = k : unused — w_topk is analytically one-hot at argmax(sim) for any k
  float* out = (float*)d_out;
  float* ws  = (float*)d_ws;

  float* qn   = ws + WS_QN;
  float* rn   = ws + WS_RN;
  float* wst  = ws + WS_WST;
  float* den  = ws + WS_DEN;
  float* sst  = ws + WS_SST;
  unsigned short* VT = (unsigned short*)(ws + WS_VT);

  float* out_content = out;
  float* out_topk    = out + BATCH*DIM;
  float* out_newmem  = out + 2*BATCH*DIM;

  hipMemsetAsync(out_content, 0, BATCH*DIM*sizeof(float), stream);
  hipMemsetAsync(den, 0, BATCH*sizeof(float), stream);
  hipLaunchKernelGGL(k_qnorm,   dim3(BATCH),       dim3(DIM), 0, stream, qry, qn);
  hipLaunchKernelGGL(k_rnorm,   dim3(NSLOTS/4),    dim3(256), 0, stream, mem, rn);
  hipLaunchKernelGGL(k_prep,    dim3(32),          dim3(256), 0, stream, val, VT);
  hipLaunchKernelGGL(k_wstats,  dim3(BATCH),       dim3(256), 0, stream, prev, sw, wst);
  hipLaunchKernelGGL(k_simfused,dim3(NROWG, NCG),  dim3(256), 0, stream, qn, mem, rn, out_content, den, sst);
  hipLaunchKernelGGL(k_finish,  dim3(BATCH),       dim3(256), 0, stream, sst, den, qn, rn, mem, out_content, out_topk);
  hipLaunchKernelGGL(k_newmem,  dim3(NSLOTS/64),   dim3(256), 0, stream, mem, VT, prev, sw, wst, out_newmem);
}